// Round 7
// baseline (348.643 us; speedup 1.0000x reference)
//
#include <hip/hip_runtime.h>
#include <hip/hip_bf16.h>

#define B_   2
#define S_   2048
#define D_   2048
#define H_   16
#define KV_  4
#define KQD_ 96
#define VD_  128
#define NQK_ 1920            // H*KQD + KV*KQD = 1536 + 384
#define M_   4096            // B*S

typedef __attribute__((ext_vector_type(8))) short bf16x8;
typedef __attribute__((ext_vector_type(4))) short bf16x4;
typedef __attribute__((ext_vector_type(4))) float f32x4;

__device__ __forceinline__ short f2bf(float f) {
    union { float f; unsigned u; } v; v.f = f;
    unsigned r = (v.u + 0x7fffu + ((v.u >> 16) & 1u)) >> 16;
    return (short)r;
}
__device__ __forceinline__ short truncbf(float f) {     // P-path: 1 VALU op
    return (short)(__float_as_uint(f) >> 16);
}
__device__ __forceinline__ float bf2f(short s) {
    union { unsigned u; float f; } v; v.u = ((unsigned)(unsigned short)s) << 16;
    return v.f;
}

__device__ __forceinline__ void glds16(const void* g, void* l) {
    __builtin_amdgcn_global_load_lds(
        (__attribute__((address_space(1))) void*)(g),
        (__attribute__((address_space(3))) void*)(l), 16, 0, 0);
}

// ---------------------------------------------------------------------------
// fp32 -> bf16 for all five inputs in one launch; dests contiguous in ws.
// ---------------------------------------------------------------------------
__global__ __launch_bounds__(256) void cvt_all(
    const float* __restrict__ hs, const float* __restrict__ wq,
    const float* __restrict__ wk, const float* __restrict__ wv,
    const float* __restrict__ wo, short* __restrict__ dst)
{
    int i = blockIdx.x * 256 + threadIdx.x;
    if (i >= 4390912) return;
    const float* s; int off;
    if      (i < 2097152) { s = hs; off = i; }
    else if (i < 2883584) { s = wq; off = i - 2097152; }
    else if (i < 3080192) { s = wk; off = i - 2883584; }
    else if (i < 3342336) { s = wv; off = i - 3080192; }
    else                  { s = wo; off = i - 3342336; }
    float4 v = ((const float4*)s)[off];
    bf16x4 o;
    o.x = f2bf(v.x); o.y = f2bf(v.y); o.z = f2bf(v.z); o.w = f2bf(v.w);
    ((bf16x4*)dst)[i] = o;
}

// ---------------------------------------------------------------------------
// GEMM: C[M x N] = A[M x K] * W[N x K]^T   (bf16 in, fp32 acc)
// Double-buffered LDS K-loop, one barrier per iter (proven win R5).
// OUT==2: fp32 row-major.  OUT==3: fused QKV (cols<NQK_ row-major into Cv,
// cols>=NQK_ transposed V^T into Cv2).
// ---------------------------------------------------------------------------
template <int OUT>
__global__ __launch_bounds__(256) void gemm_bt(
    const short* __restrict__ A, const short* __restrict__ W,
    void* __restrict__ Cv, void* __restrict__ Cv2, int M, int N, int K)
{
    __shared__ short As[2][128 * 32];   // 16 KB
    __shared__ short Ws[2][128 * 32];   // 16 KB

    const int tid  = threadIdx.x;
    const int wv   = tid >> 6;
    const int lane = tid & 63;
    const int wm   = wv >> 1, wn = wv & 1;
    const int m0   = blockIdx.x * 128;
    const int n0   = blockIdx.y * 128;
    const int l16  = lane & 15;
    const int qd   = lane >> 4;

    auto stage = [&](int k0, int buf) {
#pragma unroll
        for (int r = 0; r < 2; ++r) {
            int flat = r * 256 + tid;
            int row = flat >> 2, ch = flat & 3;
            const short* ga = A + (long)(m0 + row) * K + k0 + ch * 8;
            const short* gw = W + (long)(n0 + row) * K + k0 + ch * 8;
            int base = (r * 256 + wv * 64) * 8;
            glds16(ga, As[buf] + base);
            glds16(gw, Ws[buf] + base);
        }
    };

    stage(0, 0);   // prologue

    f32x4 acc[4][4] = {};

    for (int k0 = 0; k0 < K; k0 += 32) {
        const int buf = (k0 >> 5) & 1;
        __syncthreads();   // vmcnt(0): glds(k0) landed (issued 1 iter ago)

        bf16x8 af[4], wf[4];
#pragma unroll
        for (int i = 0; i < 4; ++i) {
            af[i] = *(const bf16x8*)(As[buf] + (wm * 64 + i * 16 + l16) * 32 + qd * 8);
            wf[i] = *(const bf16x8*)(Ws[buf] + (wn * 64 + i * 16 + l16) * 32 + qd * 8);
        }
        if (k0 + 32 < K) stage(k0 + 32, buf ^ 1);   // in flight through MFMAs

#pragma unroll
        for (int i = 0; i < 4; ++i)
#pragma unroll
            for (int j = 0; j < 4; ++j)
                acc[i][j] = __builtin_amdgcn_mfma_f32_16x16x32_bf16(
                    af[i], wf[j], acc[i][j], 0, 0, 0);
    }

    if (OUT == 2) {
        float* C = (float*)Cv;
#pragma unroll
        for (int i = 0; i < 4; ++i) {
            int row0 = m0 + wm * 64 + i * 16 + qd * 4;
#pragma unroll
            for (int j = 0; j < 4; ++j) {
                int col = n0 + wn * 64 + j * 16 + l16;
#pragma unroll
                for (int r = 0; r < 4; ++r)
                    C[(long)(row0 + r) * N + col] = acc[i][j][r];
            }
        }
    } else {  // OUT == 3
        if (n0 < NQK_) {
            short* C = (short*)Cv;
#pragma unroll
            for (int i = 0; i < 4; ++i) {
                int row0 = m0 + wm * 64 + i * 16 + qd * 4;
#pragma unroll
                for (int j = 0; j < 4; ++j) {
                    int col = n0 + wn * 64 + j * 16 + l16;
#pragma unroll
                    for (int r = 0; r < 4; ++r)
                        C[(long)(row0 + r) * NQK_ + col] = f2bf(acc[i][j][r]);
                }
            }
        } else {
            short* C = (short*)Cv2;
#pragma unroll
            for (int i = 0; i < 4; ++i) {
                int row0 = m0 + wm * 64 + i * 16 + qd * 4;
#pragma unroll
                for (int j = 0; j < 4; ++j) {
                    int vcol = n0 - NQK_ + wn * 64 + j * 16 + l16;
                    bf16x4 pk;
                    pk.x = f2bf(acc[i][j][0]); pk.y = f2bf(acc[i][j][1]);
                    pk.z = f2bf(acc[i][j][2]); pk.w = f2bf(acc[i][j][3]);
                    *(bf16x4*)(C + (long)vcol * M_ + row0) = pk;  // V^T
                }
            }
        }
    }
}

// ---------------------------------------------------------------------------
// RMSNorm + RoPE, in place on fused qk buffer (row stride NQK_).
// Q additionally pre-scaled by (1/sqrt(96))*log2(e) -> exp2-domain scores.
// ---------------------------------------------------------------------------
__global__ __launch_bounds__(256) void rms_rope(
    short* __restrict__ qk, const float* __restrict__ qw,
    const float* __restrict__ kw, const int* __restrict__ pos_ids)
{
    int wid  = (int)((blockIdx.x * 256 + threadIdx.x) >> 6);
    int lane = threadIdx.x & 63;

    short* v; const float* w; int row; float qs;
    if (wid < 65536) {                       // q: 4096 rows x 16 heads
        row = wid >> 4;
        v = qk + (long)row * NQK_ + (wid & 15) * 96;
        w = qw;
        qs = 0.14724444f;                    // (1/sqrt(96)) * log2(e)
    } else {                                 // k: 4096 rows x 4 heads
        int t = wid - 65536;
        row = t >> 2;
        v = qk + (long)row * NQK_ + 1536 + (t & 3) * 96;
        w = kw;
        qs = 1.0f;
    }

    float x0 = 0.f, x1 = 0.f;
    if (lane < 48) { x0 = bf2f(v[lane]); x1 = bf2f(v[lane + 48]); }
    float ss = x0 * x0 + x1 * x1;
#pragma unroll
    for (int off = 1; off < 64; off <<= 1) ss += __shfl_xor(ss, off, 64);
    float rr = rsqrtf(ss * (1.0f / 96.0f) + 1e-6f);

    if (lane < 48) {
        int pos = pos_ids[row];
        float y0 = (x0 * rr) * w[lane] * qs;
        float y1 = (x1 * rr) * w[lane + 48] * qs;
        float inv = exp2f(-(float)lane * (13.287712379549449f / 48.0f));
        float fr  = (float)pos * inv;
        float c, s;
        sincosf(fr, &s, &c);
        v[lane]      = f2bf(y0 * c - y1 * s);
        v[lane + 48] = f2bf(y1 * c + y0 * s);
    }
}

// ---------------------------------------------------------------------------
// Flash attention (causal, GQA 4:1). Triangle-paired q-tiles, dbuf K/V LDS,
// static-max exp2 softmax (no bias needed: 2^-M cancels in O/l).
// LDS-read dedup: wave w owns k-slice w*16.. for QK (kf 12->3 reads) and
// vd-slice 32w.. for PV (vf 16->4); P exchanged via block-shared Ps.
// l computed by ones-MFMA from the SAME truncated P the PV consumes.
// qk: fused (M x NQK_)  vt: (KV*VD x M)  out: (B,S,H*128) bf16
// ---------------------------------------------------------------------------
__global__ __launch_bounds__(256) void attn(
    const short* __restrict__ qk, const short* __restrict__ vt,
    short* __restrict__ out)
{
    __shared__ short Ks[2][64 * 104];    // 26.0 KB
    __shared__ short Vs[2][128 * 72];    // 36.0 KB
    __shared__ short Ps[64 * 72];        //  9.0 KB  (71 KB -> 2 blocks/CU)

    const int tid  = threadIdx.x;
    const int lane = tid & 63;
    const int wv   = tid >> 6;
    const int pair = blockIdx.x;          // 0..15
    const int bh   = blockIdx.y;          // 0..31
    const int b    = bh >> 4, h = bh & 15;
    const int kvh  = h >> 2;
    const int l16  = lane & 15;
    const int qd   = lane >> 4;
    const long bS  = (long)b * S_;

    const short* kbase = qk + bS * NQK_ + 1536 + kvh * 96;
    const short* vbase = vt + (long)kvh * 128 * (B_ * S_) + bS;

    const bf16x8 ones = {0x3F80, 0x3F80, 0x3F80, 0x3F80,
                         0x3F80, 0x3F80, 0x3F80, 0x3F80};   // bf16 1.0

    auto loadK = [&](int k0, bf16x8* kr) {
#pragma unroll
        for (int r = 0; r < 3; ++r) {
            int flat = r * 256 + tid;
            int row = flat / 12, ch = flat % 12;
            kr[r] = *(const bf16x8*)(kbase + (long)(k0 + row) * NQK_ + ch * 8);
        }
    };
    auto loadV = [&](int k0, bf16x8* vr) {
#pragma unroll
        for (int r = 0; r < 4; ++r) {
            int flat = r * 256 + tid;
            int row = flat >> 3, ch = flat & 7;
            vr[r] = *(const bf16x8*)(vbase + (long)row * (B_ * S_) + k0 + ch * 8);
        }
    };
    auto storeKV = [&](int buf, bf16x8* kr, bf16x8* vr) {
#pragma unroll
        for (int r = 0; r < 3; ++r) {
            int flat = r * 256 + tid;
            int row = flat / 12, ch = flat % 12;
            *(bf16x8*)(Ks[buf] + row * 104 + ch * 8) = kr[r];
        }
#pragma unroll
        for (int r = 0; r < 4; ++r) {
            int flat = r * 256 + tid;
            int row = flat >> 3, ch = flat & 7;
            *(bf16x8*)(Vs[buf] + row * 72 + ch * 8) = vr[r];
        }
    };

#pragma unroll 1
    for (int pass = 0; pass < 2; ++pass) {
        const int qt = pass == 0 ? (31 - pair) : pair;
        const int q0 = qt * 64;

        // Q fragments for ALL 4 row-groups (Q in registers; k-sliced QK)
        bf16x8 qf[4][3];
#pragma unroll
        for (int i = 0; i < 4; ++i) {
            int s = q0 + i * 16 + l16;
            const short* qp = qk + (bS + s) * NQK_ + h * 96 + qd * 8;
            qf[i][0] = *(const bf16x8*)(qp);
            qf[i][1] = *(const bf16x8*)(qp + 32);
            qf[i][2] = *(const bf16x8*)(qp + 64);
        }

        f32x4 o[4][2] = {};      // [q-group][vd-sub within this wave's slice]
        f32x4 accl[4] = {};      // l per q-group (from ones-MFMA)

        {
            bf16x8 kr[3], vr[4];
            loadK(0, kr); loadV(0, vr);
            __syncthreads();          // prior pass's LDS reads complete
            storeKV(0, kr, vr);
            __syncthreads();
        }

        for (int kt = 0; kt <= qt; ++kt) {
            const int buf = kt & 1;
            const bool more = (kt < qt);
            bf16x8 kn[3], vn[4];
            if (more) { loadK((kt + 1) * 64, kn); loadV((kt + 1) * 64, vn); }

            // QK for this wave's 16-key slice (k = wv*16 + l16), all 64 q
            bf16x8 kf[3];
#pragma unroll
            for (int f = 0; f < 3; ++f)
                kf[f] = *(const bf16x8*)(Ks[buf] + (wv * 16 + l16) * 104 + f * 32 + qd * 8);

            f32x4 sa[4];
#pragma unroll
            for (int i = 0; i < 4; ++i) {
                f32x4 a = {};
#pragma unroll
                for (int f = 0; f < 3; ++f)
                    a = __builtin_amdgcn_mfma_f32_16x16x32_bf16(qf[i][f], kf[f], a, 0, 0, 0);
                sa[i] = a;
            }
            if (kt == qt) {   // causal mask, diagonal tile only
                int kj = wv * 16 + l16;
#pragma unroll
                for (int i = 0; i < 4; ++i) {
                    int qi = i * 16 + qd * 4;
#pragma unroll
                    for (int r = 0; r < 4; ++r)
                        if (kj > qi + r) sa[i][r] = -30000.0f;
                }
            }

            // p = exp2(s)  (static bound |s|<=14.2; 2^-M bias cancels in O/l)
#pragma unroll
            for (int i = 0; i < 4; ++i)
#pragma unroll
                for (int r = 0; r < 4; ++r)
                    Ps[(i * 16 + qd * 4 + r) * 72 + wv * 16 + l16] =
                        truncbf(exp2f(sa[i][r]));

            __syncthreads();     // Ps visible to all waves

            // PV + l for this wave's 32-wide vd slice; vf/pf read once
            bf16x8 vf[2][2];
#pragma unroll
            for (int t = 0; t < 2; ++t)
#pragma unroll
                for (int c = 0; c < 2; ++c)
                    vf[t][c] = *(const bf16x8*)(
                        Vs[buf] + ((wv * 2 + t) * 16 + l16) * 72 + c * 32 + qd * 8);
#pragma unroll
            for (int i = 0; i < 4; ++i)
#pragma unroll
                for (int c = 0; c < 2; ++c) {
                    bf16x8 pf = *(const bf16x8*)(Ps + (i * 16 + l16) * 72 + c * 32 + qd * 8);
                    accl[i] = __builtin_amdgcn_mfma_f32_16x16x32_bf16(pf, ones, accl[i], 0, 0, 0);
#pragma unroll
                    for (int t = 0; t < 2; ++t)
                        o[i][t] = __builtin_amdgcn_mfma_f32_16x16x32_bf16(
                            pf, vf[t][c], o[i][t], 0, 0, 0);
                }

            if (more) {
                storeKV(buf ^ 1, kn, vn);
                __syncthreads();   // also fences Ps reads before next writes
            }
        }

        // epilogue: O / l for this wave's vd slice (accl reg r = l[q], any col)
#pragma unroll
        for (int i = 0; i < 4; ++i) {
            f32x4 inv;
#pragma unroll
            for (int r = 0; r < 4; ++r) inv[r] = 1.0f / accl[i][r];
#pragma unroll
            for (int t = 0; t < 2; ++t)
#pragma unroll
                for (int r = 0; r < 4; ++r) {
                    int s = q0 + i * 16 + qd * 4 + r;
                    out[((bS + s) * H_ + h) * 128 + (wv * 2 + t) * 16 + l16] =
                        f2bf(o[i][t][r] * inv[r]);
                }
        }
    }
}

// ---------------------------------------------------------------------------
extern "C" void kernel_launch(void* const* d_in, const int* in_sizes, int n_in,
                              void* d_out, int out_size, void* d_ws, size_t ws_size,
                              hipStream_t stream)
{
    const float* hs  = (const float*)d_in[0];
    const int*   pos = (const int*)d_in[1];
    const float* Wq  = (const float*)d_in[2];
    const float* Wk  = (const float*)d_in[3];
    const float* Wv  = (const float*)d_in[4];
    const float* Wo  = (const float*)d_in[5];
    const float* qnw = (const float*)d_in[6];
    const float* knw = (const float*)d_in[7];
    float* out = (float*)d_out;
    short* ws  = (short*)d_ws;

    short* hsb   = ws;                         // 4096 x 2048
    short* Wqkvb = hsb + (long)M_ * D_;        // 2432 x 2048 (Wq|Wk|Wv rows)
    short* Wob   = Wqkvb + (long)2432 * D_;    // 2048 x 2048
    short* qk_ws = Wob + (long)D_ * 2048;      // 4096 x 1920 (q | k fused)
    short* vt_ws = qk_ws + (long)M_ * NQK_;    // 512 x 4096  (V^T)
    short* ao_ws = vt_ws + (long)512 * M_;     // 4096 x 2048

    cvt_all<<<17152, 256, 0, stream>>>(hs, Wq, Wk, Wv, Wo, ws);

    gemm_bt<3><<<dim3(M_ / 128, 2432 / 128), 256, 0, stream>>>(
        hsb, Wqkvb, qk_ws, vt_ws, M_, 2432, D_);

    rms_rope<<<(65536 + 16384) / 4, 256, 0, stream>>>(qk_ws, qnw, knw, pos);

    attn<<<dim3(16, 32), 256, 0, stream>>>(qk_ws, vt_ws, ao_ws);

    gemm_bt<2><<<dim3(M_ / 128, D_ / 128), 256, 0, stream>>>(
        ao_ws, Wob, (void*)out, nullptr, M_, D_, H_ * VD_);
}